// Round 2
// baseline (2914.806 us; speedup 1.0000x reference)
//
#include <hip/hip_runtime.h>
#include <hip/hip_bf16.h>

typedef __bf16 bf16x8 __attribute__((ext_vector_type(8)));
typedef float  f32x4  __attribute__((ext_vector_type(4)));

__device__ __forceinline__ void store_bf8(__bf16* dst, float4 a, float4 b) {
  bf16x8 v;
  v[0] = (__bf16)a.x; v[1] = (__bf16)a.y; v[2] = (__bf16)a.z; v[3] = (__bf16)a.w;
  v[4] = (__bf16)b.x; v[5] = (__bf16)b.y; v[6] = (__bf16)b.z; v[7] = (__bf16)b.w;
  *(bf16x8*)dst = v;
}

// f32 -> bf16 bulk convert, 8 elems/thread
__global__ __launch_bounds__(256) void cvt_f32_bf16(
    const float* __restrict__ s, __bf16* __restrict__ d, long n8)
{
  long i = (long)blockIdx.x * 256 + threadIdx.x;
  if (i >= n8) return;
  const float4* sp = (const float4*)s + i * 2;
  store_bf8(d + i * 8, sp[0], sp[1]);
}

// dst[r,:] = bf16(emb[idx[r],:]), rows of 512; one 64-thread block per row
__global__ __launch_bounds__(64) void gather_cvt(
    const float* __restrict__ emb, const int* __restrict__ idx, __bf16* __restrict__ dst)
{
  const int r = blockIdx.x;
  const long row = idx[r];
  const float4* sp = (const float4*)(emb + row * 512) + threadIdx.x * 2;
  store_bf8(dst + (long)r * 512 + threadIdx.x * 8, sp[0], sp[1]);
}

// ---------------------------------------------------------------------------
// GEMM: C[M,N] (fp32) = A[M,512](bf16) @ B[N,512](bf16)^T + bias[N](fp32)
// Block = 256 threads (4 waves), block tile 64(M) x 64(N), K=512.
// MFMA 16x16x32_bf16: A-frag m=lane&15,k=quad*8+j ; B-frag n=lane&15,k=quad*8+j
// (row n of B(N,K) -> computes A@B^T) ; C/D col=lane&15, row=quad*4+r.
// ---------------------------------------------------------------------------
__global__ __launch_bounds__(256) void gemm_bt(
    const __bf16* __restrict__ A, const __bf16* __restrict__ B,
    const float* __restrict__ bias, float* __restrict__ C, int M, int N)
{
  const int wave = threadIdx.x >> 6;
  const int lane = threadIdx.x & 63;
  const int l16 = lane & 15;
  const int quad = lane >> 4;

  const int mt = blockIdx.x * 4 + wave;   // 16-row M tile
  const bool active = (mt * 16) < M;
  int row = mt * 16 + l16;
  if (row >= M) row = M - 1;              // clamp so inactive waves read safely

  const int n0 = blockIdx.y * 64;
  const __bf16* __restrict__ Ab = A + (long)row * 512 + quad * 8;

  const __bf16* bp[4];
#pragma unroll
  for (int i = 0; i < 4; ++i)
    bp[i] = B + (long)(n0 + i * 16 + l16) * 512 + quad * 8;

  f32x4 acc[4];
#pragma unroll
  for (int i = 0; i < 4; ++i) acc[i] = (f32x4){0.f, 0.f, 0.f, 0.f};

#pragma unroll
  for (int ks = 0; ks < 16; ++ks) {
    bf16x8 a = *(const bf16x8*)(Ab + ks * 32);
#pragma unroll
    for (int i = 0; i < 4; ++i) {
      bf16x8 b = *(const bf16x8*)(bp[i] + ks * 32);
      acc[i] = __builtin_amdgcn_mfma_f32_16x16x32_bf16(a, b, acc[i], 0, 0, 0);
    }
  }

  if (!active) return;
  const int crow = mt * 16 + quad * 4;
#pragma unroll
  for (int i = 0; i < 4; ++i) {
    const int n = n0 + i * 16 + l16;
    const float bv = bias ? bias[n] : 0.0f;
#pragma unroll
    for (int r = 0; r < 4; ++r)
      C[(long)(crow + r) * N + n] = acc[i][r] + bv;
  }
}

// ---------------------------------------------------------------------------
// GRU recurrence. GI = x@Wih^T + bih, fp32 (T,32,1536). 32 WGs x 128 threads.
// WG c owns hidden cols [c*16, c*16+16); its 48 Whh rows (r/z/n gates)
// converted f32->bf16 into LDS (stride 520 elems -> only 2-way bank alias, free).
// h double-buffered: fp32 master + bf16 shadow (MFMA A operand).
// Grid barrier with agent-scope fences executed by ALL threads (per-CU L1 /
// per-XCD L2 are not coherent without them).
// ---------------------------------------------------------------------------
__global__ __launch_bounds__(128) void gru_rec(
    const float* __restrict__ GI,
    const float* __restrict__ Whh,
    const float* __restrict__ bhh,
    float* __restrict__ hf32,            // 2 buffers of 32*512 fp32
    __bf16* __restrict__ hb16,           // 2 buffers of 32*512 bf16
    __bf16* __restrict__ Y,              // (T,32,512) bf16 output sequence
    unsigned* __restrict__ ctr, int T)
{
  __shared__ __align__(16) __bf16 wlds[48 * 520];
  __shared__ float ghs[3][32][17];

  const int tid = threadIdx.x;
  const int c = blockIdx.x;        // 0..31 column-slice owner
  const int w = tid >> 6;          // wave -> batch rows w*16..w*16+15
  const int lane = tid & 63;
  const int l16 = lane & 15;
  const int quad = lane >> 4;

  // Preload+convert Whh rows: local row lr=g*16+j <-> global row g*512+c*16+j
  for (int ch = tid; ch < 48 * 64; ch += 128) {
    const int lr = ch >> 6;
    const int kc = ch & 63;
    const int g = lr >> 4, j = lr & 15;
    const float4* sp = (const float4*)(Whh + (long)(g * 512 + c * 16 + j) * 512) + kc * 2;
    store_bf8(&wlds[lr * 520 + kc * 8], sp[0], sp[1]);
  }
  float bb[3];
#pragma unroll
  for (int g = 0; g < 3; ++g) bb[g] = bhh[g * 512 + c * 16 + l16];
  __syncthreads();

  for (int t = 0; t < T; ++t) {
    const int rb = t & 1, wb2 = rb ^ 1;

    // gh = h @ Whh^T (+bhh in acc init); this WG: M-tile w, 3 gate tiles
    const __bf16* __restrict__ hp = hb16 + rb * 16384 + (w * 16 + l16) * 512 + quad * 8;
    f32x4 acc[3];
#pragma unroll
    for (int g = 0; g < 3; ++g) acc[g] = (f32x4){bb[g], bb[g], bb[g], bb[g]};
#pragma unroll
    for (int ks = 0; ks < 16; ++ks) {
      bf16x8 a = *(const bf16x8*)(hp + ks * 32);
#pragma unroll
      for (int g = 0; g < 3; ++g) {
        bf16x8 b = *(const bf16x8*)&wlds[(g * 16 + l16) * 520 + ks * 32 + quad * 8];
        acc[g] = __builtin_amdgcn_mfma_f32_16x16x32_bf16(a, b, acc[g], 0, 0, 0);
      }
    }
#pragma unroll
    for (int g = 0; g < 3; ++g)
#pragma unroll
      for (int r = 0; r < 4; ++r)
        ghs[g][w * 16 + quad * 4 + r][l16] = acc[g][r];
    __syncthreads();

    // gates: 512 elements (32 batch x 16 cols), 4 per thread
    const float* __restrict__ GIt = GI + (long)t * 32 * 1536;
#pragma unroll
    for (int i = 0; i < 4; ++i) {
      const int e = tid + i * 128;
      const int b = e >> 4, j = e & 15;
      const int col = c * 16 + j;
      const float gir = GIt[b * 1536 + col];
      const float giz = GIt[b * 1536 + 512 + col];
      const float gin = GIt[b * 1536 + 1024 + col];
      const float hr = ghs[0][b][j], hz = ghs[1][b][j], hn = ghs[2][b][j];
      const float hprev = hf32[rb * 16384 + b * 512 + col];
      const float r = 1.0f / (1.0f + expf(-(gir + hr)));
      const float z = 1.0f / (1.0f + expf(-(giz + hz)));
      const float cand = tanhf(gin + r * hn);
      const float hnew = (1.0f - z) * cand + z * hprev;
      hf32[wb2 * 16384 + b * 512 + col] = hnew;
      const __bf16 hv = (__bf16)hnew;
      hb16[wb2 * 16384 + b * 512 + col] = hv;
      Y[((long)t * 32 + b) * 512 + col] = hv;
    }

    // grid barrier: flush (all threads) -> arrive -> spin -> invalidate (all)
    __syncthreads();
    __threadfence();                 // agent-scope release of our h stores
    __syncthreads();
    if (tid == 0) {
      __hip_atomic_fetch_add(ctr, 1u, __ATOMIC_RELEASE, __HIP_MEMORY_SCOPE_AGENT);
      const unsigned tgt = 32u * (unsigned)(t + 1);
      while (__hip_atomic_load(ctr, __ATOMIC_RELAXED, __HIP_MEMORY_SCOPE_AGENT) < tgt)
        __builtin_amdgcn_s_sleep(1);
    }
    __syncthreads();
    __threadfence();                 // agent-scope acquire before reading others' h
  }
}

// ---------------------------------------------------------------------------
// Workspace layout (bytes), total ~63 MB:
//  GI    @ 0         12,582,912   (2048*1536 f32, reused by all 4 projections)
//  Xenc  @ 12582912   2,097,152   (2048*512 bf16)
//  Xdec  @ 14680064   1,540,096   (1504*512 bf16)
//  Y0    @ 16220160   2,097,152
//  Y1s   @ 18317312   2,097,152   (enc layer1 seq, only hT matters)
//  D0    @ 20414464   1,540,096
//  D1    @ 21954560   1,540,096
//  Wb0-3 @ 23494656   4 x 1,572,864  (Wih bf16)
//  outWb @ 29786112  32,768,000   (32000*512 bf16)
//  h0f   @ 62554112   131,072 ; h0b @ 62685184  65,536
//  h1f   @ 62750720   131,072 ; h1b @ 62881792  65,536
//  ctrs  @ 62947328     1,024
// ---------------------------------------------------------------------------
extern "C" void kernel_launch(void* const* d_in, const int* in_sizes, int n_in,
                              void* d_out, int out_size, void* d_ws, size_t ws_size,
                              hipStream_t stream)
{
  const int* src = (const int*)d_in[0];
  const int* trg = (const int*)d_in[1];
  const float* enc_emb  = (const float*)d_in[2];
  const float* enc_Wih0 = (const float*)d_in[3];
  const float* enc_Whh0 = (const float*)d_in[4];
  const float* enc_bih0 = (const float*)d_in[5];
  const float* enc_bhh0 = (const float*)d_in[6];
  const float* enc_Wih1 = (const float*)d_in[7];
  const float* enc_Whh1 = (const float*)d_in[8];
  const float* enc_bih1 = (const float*)d_in[9];
  const float* enc_bhh1 = (const float*)d_in[10];
  const float* dec_emb  = (const float*)d_in[11];
  const float* dec_Wih0 = (const float*)d_in[12];
  const float* dec_Whh0 = (const float*)d_in[13];
  const float* dec_bih0 = (const float*)d_in[14];
  const float* dec_bhh0 = (const float*)d_in[15];
  const float* dec_Wih1 = (const float*)d_in[16];
  const float* dec_Whh1 = (const float*)d_in[17];
  const float* dec_bih1 = (const float*)d_in[18];
  const float* dec_bhh1 = (const float*)d_in[19];
  const float* out_W    = (const float*)d_in[20];
  const float* out_b    = (const float*)d_in[21];

  char* ws = (char*)d_ws;
  float*  GI    = (float*)(ws + 0);
  __bf16* Xenc  = (__bf16*)(ws + 12582912);
  __bf16* Xdec  = (__bf16*)(ws + 14680064);
  __bf16* Y0    = (__bf16*)(ws + 16220160);
  __bf16* Y1s   = (__bf16*)(ws + 18317312);
  __bf16* D0    = (__bf16*)(ws + 20414464);
  __bf16* D1    = (__bf16*)(ws + 21954560);
  __bf16* Wb0   = (__bf16*)(ws + 23494656);
  __bf16* Wb1   = (__bf16*)(ws + 25067520);
  __bf16* Wb2   = (__bf16*)(ws + 26640384);
  __bf16* Wb3   = (__bf16*)(ws + 28213248);
  __bf16* outWb = (__bf16*)(ws + 29786112);
  float*  h0f   = (float*)(ws + 62554112);
  __bf16* h0b   = (__bf16*)(ws + 62685184);
  float*  h1f   = (float*)(ws + 62750720);
  __bf16* h1b   = (__bf16*)(ws + 62881792);
  unsigned* ctrs = (unsigned*)(ws + 62947328);

  // zero initial h (buffer 0 of both chains) + barrier counters
  hipMemsetAsync(h0f, 0, 65536, stream);
  hipMemsetAsync(h0b, 0, 32768, stream);
  hipMemsetAsync(h1f, 0, 65536, stream);
  hipMemsetAsync(h1b, 0, 32768, stream);
  hipMemsetAsync(ctrs, 0, 1024, stream);

  // f32 -> bf16 conversions
  gather_cvt<<<2048, 64, 0, stream>>>(enc_emb, src, Xenc);
  gather_cvt<<<1504, 64, 0, stream>>>(dec_emb, trg, Xdec);   // rows 0..1503 = trg[:-1]
  cvt_f32_bf16<<<384, 256, 0, stream>>>(enc_Wih0, Wb0, 98304);
  cvt_f32_bf16<<<384, 256, 0, stream>>>(enc_Wih1, Wb1, 98304);
  cvt_f32_bf16<<<384, 256, 0, stream>>>(dec_Wih0, Wb2, 98304);
  cvt_f32_bf16<<<384, 256, 0, stream>>>(dec_Wih1, Wb3, 98304);
  cvt_f32_bf16<<<8000, 256, 0, stream>>>(out_W, outWb, 2048000);

  // encoder layer 0
  gemm_bt<<<dim3(32, 24), 256, 0, stream>>>(Xenc, Wb0, enc_bih0, GI, 2048, 1536);
  gru_rec<<<32, 128, 0, stream>>>(GI, enc_Whh0, enc_bhh0, h0f, h0b, Y0, ctrs + 0, 64);
  // encoder layer 1 (final h of both layers lands in buffer 0: T=64 even)
  gemm_bt<<<dim3(32, 24), 256, 0, stream>>>(Y0, Wb1, enc_bih1, GI, 2048, 1536);
  gru_rec<<<32, 128, 0, stream>>>(GI, enc_Whh1, enc_bhh1, h1f, h1b, Y1s, ctrs + 32, 64);
  // decoder layer 0 (h0 = enc layer0 final, already in buffer 0)
  gemm_bt<<<dim3(24, 24), 256, 0, stream>>>(Xdec, Wb2, dec_bih0, GI, 1504, 1536);
  gru_rec<<<32, 128, 0, stream>>>(GI, dec_Whh0, dec_bhh0, h0f, h0b, D0, ctrs + 64, 47);
  // decoder layer 1 (h0 = enc layer1 final)
  gemm_bt<<<dim3(24, 24), 256, 0, stream>>>(D0, Wb3, dec_bih1, GI, 1504, 1536);
  gru_rec<<<32, 128, 0, stream>>>(GI, dec_Whh1, dec_bhh1, h1f, h1b, D1, ctrs + 96, 47);

  // logits = D1 @ out_W^T + out_b  (fp32 out, 1504 x 32000)
  gemm_bt<<<dim3(24, 500), 256, 0, stream>>>(D1, outWb, out_b, (float*)d_out, 1504, 32000);
}